// Round 15
// baseline (295.365 us; speedup 1.0000x reference)
//
#include <hip/hip_runtime.h>
#include <stdint.h>

typedef __attribute__((ext_vector_type(8))) short short8;
typedef __attribute__((ext_vector_type(4))) float f32x4;
typedef unsigned short u16;
typedef unsigned int u32;

#define NTOK 4096   // B*S
#define E 2048
#define S 2048
#define NH 16
#define NKVH 4
#define HD 128
#define NQKV 3072   // E + 512 + 512

__device__ __forceinline__ float bf2f(u16 u) {
    return __uint_as_float(((u32)u) << 16);
}
__device__ __forceinline__ u16 f2bf(float f) {
    u32 u = __float_as_uint(f);
    u32 r = (u + 0x7fffu + ((u >> 16) & 1u)) >> 16;
    return (u16)r;
}
__device__ __forceinline__ void gload_lds16(const u16* g, u16* l) {
    __builtin_amdgcn_global_load_lds(
        (const __attribute__((address_space(1))) unsigned int*)(g),
        (__attribute__((address_space(3))) unsigned int*)(l), 16, 0, 0);
}

// ------- fused fp32 -> bf16 cast of all 5 tensors + RoPE cos/sin LUT build -------
// blocks >= 18432 build tab[s][i] = (cos, sin)(s * 10000^(-2i/128)), 2048x64 float2.
#define CASTBLKS 18432
__global__ void cast5(const float* __restrict__ x, const float* __restrict__ wq,
                      const float* __restrict__ wk, const float* __restrict__ wv,
                      const float* __restrict__ wo,
                      u16* __restrict__ xb, u16* __restrict__ wqkvb,
                      u16* __restrict__ wob, float* __restrict__ tab) {
    if (blockIdx.x >= CASTBLKS) {
        int idx2 = (blockIdx.x - CASTBLKS) * 256 + threadIdx.x;   // 0..131071
        int sct = idx2 >> 6, ln2 = idx2 & 63;
        float freq = expf(ln2 * -0.14391156831212787f);
        float ang = (float)sct * freq;
        float sn, cs;
        sincosf(ang, &sn, &cs);
        ((float2*)tab)[idx2] = (float2){cs, sn};
        return;
    }
    int i = blockIdx.x * 256 + threadIdx.x;
    const float* s; u16* d; int rel;
    if (i < 2097152)      { s = x;  d = xb;  rel = i; }
    else if (i < 3145728) { s = wq; d = wqkvb; rel = i - 2097152; }
    else if (i < 3407872) { s = wk; d = wqkvb + 4194304; rel = i - 3145728; }
    else if (i < 3670016) { s = wv; d = wqkvb + 5242880; rel = i - 3407872; }
    else                  { s = wo; d = wob; rel = i - 3670016; }
    float4 v = *(const float4*)(s + (size_t)rel * 4);
    ushort4 o;
    o.x = f2bf(v.x); o.y = f2bf(v.y); o.z = f2bf(v.z); o.w = f2bf(v.w);
    *(ushort4*)(d + (size_t)rel * 4) = o;
}

// shared swizzle helpers (rule-21 involution: linear gload_lds dest, inverse-swizzled
// global source, swizzled ds_read)
#define LADDR(row, ko) ((row) * 64 + ((ko) ^ (((row) & 7) << 3)))
#define GSB   __builtin_amdgcn_sched_barrier(0)
#define GBAR  __builtin_amdgcn_s_barrier()
#define LGKM0 do { asm volatile("s_waitcnt lgkmcnt(0)" ::: "memory"); GSB; } while (0)

__device__ __forceinline__ void stage1(u16* lds, const u16* g, int row0,
                                       int kt, int K, int tid) {
    const int rr = tid >> 3;
    const int chunk = (tid & 7) ^ (rr & 7);
    gload_lds16(g + (size_t)(row0 + rr) * K + kt + chunk * 8,
                lds + (row0 + (tid >> 6) * 8) * 64);
}

// ======================= 128x192 2-barrier bf16 GEMM (QKV projection) ================
// 512 blocks = 2 blocks/CU (80 KiB LDS); validated R12.
__global__ __launch_bounds__(512, 2)
void gemm_qkv(const u16* __restrict__ A, const u16* __restrict__ Bt,
              float* __restrict__ C, int M, int N, int K) {
    __shared__ u16 As2[2 * 8192];    // [buf][128][64]
    __shared__ u16 Bs2[2 * 12288];   // [buf][192][64]
    const int tid = threadIdx.x;
    const int w = tid >> 6, lane = tid & 63;
    const int lr = lane & 15, quad = lane >> 4;
    const int qo = quad * 8;
    const int wr = w >> 2, wc = w & 3;
    const int am = wr * 64;
    const int bn = wc * 48;

    const int nbx = N / 192;         // 16
    int wg = blockIdx.x;
    {
        const int nwg = gridDim.x;
        const int q = nwg >> 3, r = nwg & 7;
        const int xcd = wg & 7, loc = wg >> 3;
        wg = (xcd < r ? xcd * (q + 1) : r * (q + 1) + (xcd - r) * q) + loc;
    }
    const int n0 = (wg % nbx) * 192;
    const int m0 = (wg / nbx) * 128;

    const u16* gA = A + (size_t)m0 * K;
    const u16* gB = Bt + (size_t)n0 * K;
    const int nt = K >> 6;

    f32x4 acc[4][3];
#pragma unroll
    for (int mi = 0; mi < 4; mi++)
#pragma unroll
        for (int ni = 0; ni < 3; ni++)
            acc[mi][ni] = (f32x4){0.f, 0.f, 0.f, 0.f};

    short8 af[4][2], bf[3][2];

    stage1(As2, gA, 0, 0, K, tid);
    stage1(As2, gA, 64, 0, K, tid);
#pragma unroll
    for (int r = 0; r < 3; r++) stage1(Bs2, gB, r * 64, 0, K, tid);
    if (nt > 1) {
        stage1(As2 + 8192, gA, 0, 64, K, tid);
        stage1(As2 + 8192, gA, 64, 64, K, tid);
        stage1(Bs2 + 12288, gB, 0, 64, K, tid);
        stage1(Bs2 + 12288, gB, 64, 64, K, tid);
        asm volatile("s_waitcnt vmcnt(4)" ::: "memory");
    } else {
        asm volatile("s_waitcnt vmcnt(0)" ::: "memory");
    }
    GSB; GBAR;

    for (int t = 0; t < nt; ++t) {
        const int pb = t & 1;
        u16* Ap = As2 + pb * 8192;
        u16* Bp = Bs2 + pb * 12288;
        u16* Bn = Bs2 + (pb ^ 1) * 12288;
        const int kt1 = (t + 1) << 6, kt2 = (t + 2) << 6;

#pragma unroll
        for (int mi = 0; mi < 4; mi++)
#pragma unroll
            for (int kk = 0; kk < 2; kk++)
                af[mi][kk] = *(const short8*)&Ap[LADDR(am + mi * 16 + lr, kk * 32 + qo)];
#pragma unroll
        for (int ni = 0; ni < 3; ni++)
#pragma unroll
            for (int kk = 0; kk < 2; kk++)
                bf[ni][kk] = *(const short8*)&Bp[LADDR(bn + ni * 16 + lr, kk * 32 + qo)];
        if (t + 1 < nt) stage1(Bn, gB, 128, kt1, K, tid);
        GSB; GBAR; LGKM0;
        __builtin_amdgcn_s_setprio(1);
#pragma unroll
        for (int mi = 0; mi < 4; mi++)
#pragma unroll
            for (int ni = 0; ni < 3; ni++)
#pragma unroll
                for (int kk = 0; kk < 2; kk++)
                    acc[mi][ni] = __builtin_amdgcn_mfma_f32_16x16x32_bf16(
                        af[mi][kk], bf[ni][kk], acc[mi][ni], 0, 0, 0);
        __builtin_amdgcn_s_setprio(0);
        if (t + 2 < nt) {
            stage1(Ap, gA, 0, kt2, K, tid);
            stage1(Ap, gA, 64, kt2, K, tid);
            stage1(Bp, gB, 0, kt2, K, tid);
            stage1(Bp, gB, 64, kt2, K, tid);
        }
        if (t + 2 >= nt) {
            asm volatile("s_waitcnt vmcnt(0)" ::: "memory");
        } else {
            asm volatile("s_waitcnt vmcnt(4)" ::: "memory");
        }
        GSB; GBAR;
    }

#pragma unroll
    for (int mi = 0; mi < 4; mi++)
#pragma unroll
        for (int ni = 0; ni < 3; ni++) {
            const int row = m0 + am + mi * 16 + quad * 4;
            const int col = n0 + bn + ni * 16 + lr;
            f32x4 v = acc[mi][ni];
            C[(size_t)(row + 0) * N + col] = v[0];
            C[(size_t)(row + 1) * N + col] = v[1];
            C[(size_t)(row + 2) * N + col] = v[2];
            C[(size_t)(row + 3) * N + col] = v[3];
        }
}

// ======================= 128x128 2-barrier bf16 GEMM (output projection) =============
__global__ __launch_bounds__(512, 2)
void gemm_proj(const u16* __restrict__ A, const u16* __restrict__ Bt,
               float* __restrict__ C, int M, int N, int K) {
    __shared__ u16 As2[2 * 8192];
    __shared__ u16 Bs2[2 * 8192];
    const int tid = threadIdx.x;
    const int w = tid >> 6, lane = tid & 63;
    const int lr = lane & 15, quad = lane >> 4;
    const int qo = quad * 8;
    const int wr = w >> 2, wc = w & 3;
    const int am = wr * 64;
    const int bn = wc * 32;

    const int nbx = N >> 7;          // 16
    int wg = blockIdx.x;
    {
        const int nwg = gridDim.x;
        const int q = nwg >> 3, r = nwg & 7;
        const int xcd = wg & 7, loc = wg >> 3;
        wg = (xcd < r ? xcd * (q + 1) : r * (q + 1) + (xcd - r) * q) + loc;
    }
    const int n0 = (wg % nbx) << 7;
    const int m0 = (wg / nbx) << 7;

    const u16* gA = A + (size_t)m0 * K;
    const u16* gB = Bt + (size_t)n0 * K;
    const int nt = K >> 6;

    f32x4 acc[4][2];
#pragma unroll
    for (int mi = 0; mi < 4; mi++)
#pragma unroll
        for (int ni = 0; ni < 2; ni++)
            acc[mi][ni] = (f32x4){0.f, 0.f, 0.f, 0.f};

    short8 af[4][2], bf[2][2];

    stage1(As2, gA, 0, 0, K, tid);
    stage1(As2, gA, 64, 0, K, tid);
    stage1(Bs2, gB, 0, 0, K, tid);
    stage1(Bs2, gB, 64, 0, K, tid);
    if (nt > 1) {
        stage1(As2 + 8192, gA, 0, 64, K, tid);
        stage1(As2 + 8192, gA, 64, 64, K, tid);
        stage1(Bs2 + 8192, gB, 0, 64, K, tid);
        asm volatile("s_waitcnt vmcnt(3)" ::: "memory");
    } else {
        asm volatile("s_waitcnt vmcnt(0)" ::: "memory");
    }
    GSB; GBAR;

    for (int t = 0; t < nt; ++t) {
        const int pb = t & 1;
        u16* Ap = As2 + pb * 8192;
        u16* Bp = Bs2 + pb * 8192;
        u16* Bn = Bs2 + (pb ^ 1) * 8192;
        const int kt1 = (t + 1) << 6, kt2 = (t + 2) << 6;

#pragma unroll
        for (int mi = 0; mi < 4; mi++)
#pragma unroll
            for (int kk = 0; kk < 2; kk++)
                af[mi][kk] = *(const short8*)&Ap[LADDR(am + mi * 16 + lr, kk * 32 + qo)];
#pragma unroll
        for (int ni = 0; ni < 2; ni++)
#pragma unroll
            for (int kk = 0; kk < 2; kk++)
                bf[ni][kk] = *(const short8*)&Bp[LADDR(bn + ni * 16 + lr, kk * 32 + qo)];
        if (t + 1 < nt) stage1(Bn, gB, 64, kt1, K, tid);
        GSB; GBAR; LGKM0;
        __builtin_amdgcn_s_setprio(1);
#pragma unroll
        for (int mi = 0; mi < 4; mi++)
#pragma unroll
            for (int ni = 0; ni < 2; ni++)
#pragma unroll
                for (int kk = 0; kk < 2; kk++)
                    acc[mi][ni] = __builtin_amdgcn_mfma_f32_16x16x32_bf16(
                        af[mi][kk], bf[ni][kk], acc[mi][ni], 0, 0, 0);
        __builtin_amdgcn_s_setprio(0);
        if (t + 2 < nt) {
            stage1(Ap, gA, 0, kt2, K, tid);
            stage1(Ap, gA, 64, kt2, K, tid);
            stage1(Bp, gB, 0, kt2, K, tid);
        }
        if (t + 2 >= nt) {
            asm volatile("s_waitcnt vmcnt(0)" ::: "memory");
        } else {
            asm volatile("s_waitcnt vmcnt(3)" ::: "memory");
        }
        GSB; GBAR;
    }

#pragma unroll
    for (int mi = 0; mi < 4; mi++)
#pragma unroll
        for (int ni = 0; ni < 2; ni++) {
            const int row = m0 + am + mi * 16 + quad * 4;
            const int col = n0 + bn + ni * 16 + lr;
            f32x4 v = acc[mi][ni];
            C[(size_t)(row + 0) * N + col] = v[0];
            C[(size_t)(row + 1) * N + col] = v[1];
            C[(size_t)(row + 2) * N + col] = v[2];
            C[(size_t)(row + 3) * N + col] = v[3];
        }
}

// ---------------- prep: K RMSNorm+RoPE (LUT) + V-transpose. Q moved into attn. ------
#define LDT 65
#define KBLKS 4096
__global__ __launch_bounds__(256)
void prep(const float* __restrict__ qkv, const float* __restrict__ kw,
          const float* __restrict__ tab,
          u16* __restrict__ kdst, u16* __restrict__ vdst) {
    __shared__ u16 Ts[128 * LDT];
    if (blockIdx.x < KBLKS) {
        int p = blockIdx.x * 4 + (threadIdx.x >> 6);   // 0..16383
        int lane = threadIdx.x & 63;
        int n = p >> 2;
        int h = p & 3;
        int b = n >> 11;
        int s = n & 2047;
        const float* row = qkv + (size_t)n * NQKV + 2048 + h * HD;
        float t1 = row[lane];
        float t2 = row[lane + 64];
        float ss = t1 * t1 + t2 * t2;
#pragma unroll
        for (int o = 1; o < 64; o <<= 1) ss += __shfl_xor(ss, o);
        float r = rsqrtf(ss * (1.f / 128.f) + 1e-6f);
        float a1 = t1 * r * kw[lane];
        float a2 = t2 * r * kw[lane + 64];
        float2 csn = ((const float2*)tab)[(s << 6) + lane];
        float o1 = a1 * csn.x - a2 * csn.y;
        float o2 = a2 * csn.x + a1 * csn.y;
        size_t base = (((size_t)(b * NKVH + h)) * S + s) * HD;
        kdst[base + lane] = f2bf(o1);
        kdst[base + 64 + lane] = f2bf(o2);
    } else {
        const int idx = blockIdx.x - KBLKS;
        const int t = threadIdx.x;
        const int s0 = (idx & 31) * 64;
        const int kh = (idx >> 5) & 3;
        const int b = idx >> 7;
        const float* base = qkv + ((size_t)(b * S + s0)) * NQKV + 2560 + kh * HD;
#pragma unroll
        for (int i = 0; i < 8; i++) {
            int ii = i * 256 + t;
            int r = ii >> 5, c4 = (ii & 31) * 4;
            float4 v = *(const float4*)(base + (size_t)r * NQKV + c4);
            Ts[(c4 + 0) * LDT + r] = f2bf(v.x);
            Ts[(c4 + 1) * LDT + r] = f2bf(v.y);
            Ts[(c4 + 2) * LDT + r] = f2bf(v.z);
            Ts[(c4 + 3) * LDT + r] = f2bf(v.w);
        }
        __syncthreads();
        u16* obase = vdst + ((size_t)(b * NKVH + kh) * HD) * S + s0;
#pragma unroll
        for (int i = 0; i < 4; i++) {
            int ii = i * 256 + t;
            int d = ii >> 3, s8 = (ii & 7) * 8;
            const u16* row = &Ts[d * LDT + s8];
            short8 o;
#pragma unroll
            for (int j = 0; j < 8; j++) o[j] = (short)row[j];
            *(short8*)(obase + (size_t)d * S + s8) = o;
        }
    }
}

// ---------------- MFMA flash attention + fused Q RMSNorm/RoPE prologue --------------
// R8 hot loop frozen. Q prologue writes bf16 Q into Ks scratch; R14 used a LINEAR
// [64][128] layout -> 16-way bank conflict on the qf short8 reads + 8-way on writes
// (SQ_LDS_BANK_CONFLICT 589824). Fix: XOR-swizzle at 8B-chunk granularity,
// chunk ^= (row&7)<<2, applied on BOTH write and read (involution). Reads now span
// 8 distinct 16B slots per quad-class -> 32 banks, 2-way (free per m136).
#define QSC(row, chunk) ((row) * 128 + (((chunk) ^ (((row) & 7) << 2)) << 2))
#define KSX(key, cb) ((key) * 128 + ((((cb) ^ ((key) & 15))) * 8))
#define VSX(d, cb)   ((d) * 64 + ((((cb) ^ ((d) & 7))) * 8))
#define PSX(row, cb) ((row) * 64 + ((((cb) ^ ((row) & 7))) * 8))
#define QBLK 64

__global__ __launch_bounds__(256, 4)
void attn_mfma(const float* __restrict__ qkv, const float* __restrict__ qw,
               const float* __restrict__ tab,
               const u16* __restrict__ ka, const u16* __restrict__ vt,
               u16* __restrict__ out) {
    __shared__ u16 Ks[64 * 128];
    __shared__ u16 Vs[128 * 64];
    __shared__ u16 Ps[64 * 64];
    const int tid = threadIdx.x;
    const int w = tid >> 6, lane = tid & 63;
    const int lr = lane & 15, quad = lane >> 4;

    const int bid = blockIdx.x;
    const int g = bid >> 8, p = bid & 255;
    const int j = p >> 5, hb = p & 31;
    int qt;
    if (g == 0) qt = 31 - j;
    else if (g == 1) qt = 23 - j;
    else if (g == 2) qt = 8 + j;
    else qt = 7 - j;
    const int h = hb >> 1, b = hb & 1;
    const int kh = h >> 2;
    const int q0 = qt * QBLK;
    const int qg0 = q0 + w * 16;          // this wave's 16 queries

    const float KQK = 0.0051006974f;      // 2/(sqrt(128)*50) * log2(e)
    const float KP  = -144.26950408889634f; // -100 * log2(e)

    const u16* kbase0 = ka + (((size_t)(b * NKVH + kh)) * S) * HD;
    const u16* vtbase0 = vt + ((size_t)(b * NKVH + kh) * HD) * S;

    // ---- fused Q RMSNorm+RoPE into Ks (swizzled scratch; K staging reuses Ks) ----
    {
        const int rowL = lane >> 2, q4 = lane & 3;   // 4 lanes per row, 16 rows/wave
        const int sl = w * 16 + rowL;                // block-local row 0..63
        const int sg = q0 + sl;                      // global seq position
        const float* qr = qkv + ((size_t)(b * S + sg)) * NQKV + h * HD + q4 * 16;
        float ss = 0.f;
#pragma unroll
        for (int c = 0; c < 4; c++) {
            float4 u = *(const float4*)(qr + c * 4);
            float4 vv = *(const float4*)(qr + 64 + c * 4);
            ss += u.x * u.x + u.y * u.y + u.z * u.z + u.w * u.w;
            ss += vv.x * vv.x + vv.y * vv.y + vv.z * vv.z + vv.w * vv.w;
        }
        ss += __shfl_xor(ss, 1);
        ss += __shfl_xor(ss, 2);
        const float rn = rsqrtf(ss * (1.f / 128.f) + 1e-6f);
#pragma unroll
        for (int c = 0; c < 4; c++) {                // reload (L1-hot), transform
            float4 u = *(const float4*)(qr + c * 4);
            float4 vv = *(const float4*)(qr + 64 + c * 4);
            float4 w1 = *(const float4*)(qw + q4 * 16 + c * 4);
            float4 w2 = *(const float4*)(qw + 64 + q4 * 16 + c * 4);
            ushort4 p1, p2;
            const float* pu = (const float*)&u;
            const float* pv = (const float*)&vv;
            const float* pw1 = (const float*)&w1;
            const float* pw2 = (const float*)&w2;
            u16* d1 = (u16*)&p1;
            u16* d2 = (u16*)&p2;
#pragma unroll
            for (int k = 0; k < 4; k++) {
                int dd = q4 * 16 + c * 4 + k;        // 0..63
                float2 csn = ((const float2*)tab)[(sg << 6) + dd];
                float a1 = pu[k] * rn * pw1[k];
                float a2 = pv[k] * rn * pw2[k];
                d1[k] = f2bf(a1 * csn.x - a2 * csn.y);
                d2[k] = f2bf(a2 * csn.x + a1 * csn.y);
            }
            // swizzled chunk stores: chunk = half*16 + q4*4 + c  (4 u16 per chunk)
            *(ushort4*)(&Ks[QSC(sl, q4 * 4 + c)]) = p1;
            *(ushort4*)(&Ks[QSC(sl, 16 + q4 * 4 + c)]) = p2;
        }
    }
    __syncthreads();

    short8 qf[4];
    {
        const int qrow = w * 16 + lr;
        // logical u16 offset c*32+quad*8 = chunk (c*8+quad*2), swizzled like writes
#pragma unroll
        for (int c = 0; c < 4; c++)
            qf[c] = *(const short8*)(&Ks[QSC(qrow, c * 8 + quad * 2)]);
    }

    f32x4 O[8];
#pragma unroll
    for (int dt = 0; dt < 8; dt++) O[dt] = (f32x4){0.f, 0.f, 0.f, 0.f};
    float l[4] = {0.f, 0.f, 0.f, 0.f};

    const int jt0 = (q0 >= 1024) ? (q0 - 1024) : 0;
    const int jtend = q0;                 // diagonal tile
    const int qmin = qg0, qmax = qg0 + 15;

    for (int jt = jt0; jt <= jtend; jt += 64) {
        const u16* kbase = kbase0 + (size_t)jt * HD;
        const u16* vtbase = vtbase0 + jt;
        __syncthreads();
#pragma unroll
        for (int i = 0; i < 4; i++) {
            int idx = i * 256 + tid;
            int key = idx >> 4, cbk = (idx & 15) ^ (key & 15);
            gload_lds16(kbase + (size_t)key * HD + cbk * 8,
                        &Ks[(i * 256 + w * 64) * 8]);
            int dd = idx >> 3, cbv = (idx & 7) ^ (dd & 7);
            gload_lds16(vtbase + (size_t)dd * S + cbv * 8,
                        &Vs[(i * 256 + w * 64) * 8]);
        }
        __syncthreads();

        u16* Pw = &Ps[w * 16 * 64];
        bool any = false;

#pragma unroll
        for (int kt = 0; kt < 4; kt++) {
            const int keymin = jt + kt * 16;
            bool need = (keymin <= qmax) && (keymin + 15 >= qmin - 1023);
            bool full = (keymin + 15 <= qmin) && (keymin >= qmax - 1023);
            if (need) {
                any = true;
                f32x4 a = (f32x4){0.f, 0.f, 0.f, 0.f};
                __builtin_amdgcn_s_setprio(1);
#pragma unroll
                for (int c = 0; c < 4; c++) {
                    short8 kf = *(const short8*)(&Ks[KSX(kt * 16 + lr, 4 * c + quad)]);
                    a = __builtin_amdgcn_mfma_f32_16x16x32_bf16(qf[c], kf, a, 0, 0, 0);
                }
                __builtin_amdgcn_s_setprio(0);
#pragma unroll
                for (int r = 0; r < 4; r++) {
                    float t = __builtin_amdgcn_exp2f(a[r] * KQK);
                    float p2 = __builtin_amdgcn_exp2f(
                        KP * __builtin_amdgcn_rcpf(t + 1.f));
                    if (!full) {
                        int rel = keymin + lr - (qg0 + quad * 4 + r);
                        bool valid = (rel <= 0) && (rel > -1024);
                        p2 = valid ? p2 : 0.f;
                    }
                    l[r] += p2;
                    Pw[PSX(quad * 4 + r, kt * 2 + (lr >> 3)) + (lr & 7)] =
                        (u16)(__float_as_uint(p2) >> 16);
                }
            } else {
#pragma unroll
                for (int r = 0; r < 4; r++)
                    Pw[PSX(quad * 4 + r, kt * 2 + (lr >> 3)) + (lr & 7)] = 0;
            }
        }

        if (any) {
            __builtin_amdgcn_s_setprio(1);
#pragma unroll
            for (int c2 = 0; c2 < 2; c2++) {
                short8 pf = *(const short8*)(&Pw[PSX(lr, c2 * 4 + quad)]);
#pragma unroll
                for (int dt = 0; dt < 8; dt++) {
                    short8 vf = *(const short8*)(&Vs[VSX(dt * 16 + lr, c2 * 4 + quad)]);
                    O[dt] = __builtin_amdgcn_mfma_f32_16x16x32_bf16(pf, vf, O[dt], 0, 0, 0);
                }
            }
            __builtin_amdgcn_s_setprio(0);
        }
    }

#pragma unroll
    for (int r = 0; r < 4; r++) {
        l[r] += __shfl_xor(l[r], 1);
        l[r] += __shfl_xor(l[r], 2);
        l[r] += __shfl_xor(l[r], 4);
        l[r] += __shfl_xor(l[r], 8);
    }
#pragma unroll
    for (int r = 0; r < 4; r++) {
        float inv = 1.f / l[r];
        u16* orow = out + ((size_t)(b * S + qg0 + quad * 4 + r)) * E + h * HD;
#pragma unroll
        for (int dt = 0; dt < 8; dt++)
            orow[dt * 16 + lr] = f2bf(O[dt][r] * inv);
    }
}

// ---------------- residual + LayerNorm ----------------
__global__ __launch_bounds__(256)
void ln_kernel(const float* __restrict__ x, const float* __restrict__ pr,
               const float* __restrict__ g, const float* __restrict__ be,
               float* __restrict__ out) {
    int n = blockIdx.x;
    int tid = threadIdx.x;
    const float* xr = x + (size_t)n * E;
    const float* p = pr + (size_t)n * E;
    float y[8];
    float s = 0.f, ss = 0.f;
#pragma unroll
    for (int i = 0; i < 2; i++) {
        float4 a = *(const float4*)(xr + tid * 8 + i * 4);
        float4 b = *(const float4*)(p + tid * 8 + i * 4);
        float v0 = a.x + b.x, v1 = a.y + b.y, v2 = a.z + b.z, v3 = a.w + b.w;
        y[i * 4 + 0] = v0; y[i * 4 + 1] = v1; y[i * 4 + 2] = v2; y[i * 4 + 3] = v3;
        s += v0 + v1 + v2 + v3;
        ss += v0 * v0 + v1 * v1 + v2 * v2 + v3 * v3;
    }
#pragma unroll
    for (int o = 1; o < 64; o <<= 1) {
        s += __shfl_xor(s, o);
        ss += __shfl_xor(ss, o);
    }
    __shared__ float r0[4], r1[4];
    int w = tid >> 6;
    if ((tid & 63) == 0) { r0[w] = s; r1[w] = ss; }
    __syncthreads();
    s = r0[0] + r0[1] + r0[2] + r0[3];
    ss = r1[0] + r1[1] + r1[2] + r1[3];
    float mu = s * (1.f / 2048.f);
    float var = ss * (1.f / 2048.f) - mu * mu;
    float rs = rsqrtf(var + 1e-5f);
    float* orow = out + (size_t)n * E;
#pragma unroll
    for (int i = 0; i < 8; i++) {
        int c = tid * 8 + i;
        orow[c] = (y[i] - mu) * rs * g[c] + be[c];
    }
}

// ---------------- launch ----------------
extern "C" void kernel_launch(void* const* d_in, const int* in_sizes, int n_in,
                              void* d_out, int out_size, void* d_ws, size_t ws_size,
                              hipStream_t stream) {
    (void)in_sizes; (void)n_in; (void)out_size; (void)ws_size;
    const float* x   = (const float*)d_in[0];
    const float* Wq  = (const float*)d_in[1];
    const float* Wk  = (const float*)d_in[2];
    const float* Wv  = (const float*)d_in[3];
    const float* Wo  = (const float*)d_in[4];
    const float* qnw = (const float*)d_in[5];
    const float* knw = (const float*)d_in[6];
    const float* lng = (const float*)d_in[7];
    const float* lnb = (const float*)d_in[8];
    float* out = (float*)d_out;

    char* ws = (char*)d_ws;
    size_t off = 0;
    auto alloc = [&](size_t bytes) -> char* {
        char* pp = ws + off;
        off = (off + bytes + 255) & ~(size_t)255;
        return pp;
    };
    u16*  xb     = (u16*)alloc((size_t)NTOK * E * 2);       // later reused as attn_out
    u16*  Wqkvb  = (u16*)alloc((size_t)NQKV * E * 2);       // [Wq; Wk; Wv]
    u16*  Wob    = (u16*)alloc((size_t)E * E * 2);
    float* qkvraw= (float*)alloc((size_t)NTOK * NQKV * 4);  // 50.3MB; reused as proj
    u16*  kaa    = (u16*)alloc((size_t)NTOK * 512 * 2);
    u16*  vtt    = (u16*)alloc((size_t)NTOK * 512 * 2);
    float* tab   = (float*)alloc((size_t)S * 64 * 8);       // RoPE cos/sin LUT, 1MB
    u16*  attn_o = xb;
    float* proj  = qkvraw;   // 33.5MB needed; qkvraw (50.3MB) dead after attn

    cast5<<<dim3(CASTBLKS + 512), 256, 0, stream>>>(x, Wq, Wk, Wv, Wo, xb, Wqkvb,
                                                    Wob, tab);

    // 128x192 tiles -> 32x16 = 512 blocks (2 blocks/CU), 2-barrier K-loop
    gemm_qkv<<<dim3(512), 512, 0, stream>>>(xb, Wqkvb, qkvraw, NTOK, NQKV, E);

    // K rmsrope (LUT) + V transpose; Q handled inside attn
    prep<<<dim3(KBLKS + 256), 256, 0, stream>>>(qkvraw, knw, tab, kaa, vtt);

    // CU-balanced 1024-block grid (4/CU); fused Q rmsrope prologue (swizzled scratch)
    attn_mfma<<<dim3(1024), 256, 0, stream>>>(qkvraw, qnw, tab, kaa, vtt, attn_o);

    // 128x128 tiles -> 32x16 = 512 blocks (2 blocks/CU), 2-barrier K-loop
    gemm_proj<<<dim3(512), 512, 0, stream>>>(attn_o, Wob, proj, NTOK, E, E);

    ln_kernel<<<dim3(NTOK), 256, 0, stream>>>(x, proj, lng, lnb, out);
}

// Round 16
// 289.280 us; speedup vs baseline: 1.0210x; 1.0210x over previous
//
#include <hip/hip_runtime.h>
#include <stdint.h>

typedef __attribute__((ext_vector_type(8))) short short8;
typedef __attribute__((ext_vector_type(4))) float f32x4;
typedef unsigned short u16;
typedef unsigned int u32;

#define NTOK 4096   // B*S
#define E 2048
#define S 2048
#define NH 16
#define NKVH 4
#define HD 128
#define NQKV 3072   // E + 512 + 512

__device__ __forceinline__ float bf2f(u16 u) {
    return __uint_as_float(((u32)u) << 16);
}
__device__ __forceinline__ u16 f2bf(float f) {
    u32 u = __float_as_uint(f);
    u32 r = (u + 0x7fffu + ((u >> 16) & 1u)) >> 16;
    return (u16)r;
}
__device__ __forceinline__ void gload_lds16(const u16* g, u16* l) {
    __builtin_amdgcn_global_load_lds(
        (const __attribute__((address_space(1))) unsigned int*)(g),
        (__attribute__((address_space(3))) unsigned int*)(l), 16, 0, 0);
}

// ------- fused fp32 -> bf16 cast of all 5 tensors + RoPE cos/sin LUT build -------
// blocks >= 18432 build tab[s][i] = (cos, sin)(s * 10000^(-2i/128)), 2048x64 float2.
#define CASTBLKS 18432
__global__ void cast5(const float* __restrict__ x, const float* __restrict__ wq,
                      const float* __restrict__ wk, const float* __restrict__ wv,
                      const float* __restrict__ wo,
                      u16* __restrict__ xb, u16* __restrict__ wqkvb,
                      u16* __restrict__ wob, float* __restrict__ tab) {
    if (blockIdx.x >= CASTBLKS) {
        int idx2 = (blockIdx.x - CASTBLKS) * 256 + threadIdx.x;   // 0..131071
        int sct = idx2 >> 6, ln2 = idx2 & 63;
        float freq = expf(ln2 * -0.14391156831212787f);
        float ang = (float)sct * freq;
        float sn, cs;
        sincosf(ang, &sn, &cs);
        ((float2*)tab)[idx2] = (float2){cs, sn};
        return;
    }
    int i = blockIdx.x * 256 + threadIdx.x;
    const float* s; u16* d; int rel;
    if (i < 2097152)      { s = x;  d = xb;  rel = i; }
    else if (i < 3145728) { s = wq; d = wqkvb; rel = i - 2097152; }
    else if (i < 3407872) { s = wk; d = wqkvb + 4194304; rel = i - 3145728; }
    else if (i < 3670016) { s = wv; d = wqkvb + 5242880; rel = i - 3407872; }
    else                  { s = wo; d = wob; rel = i - 3670016; }
    float4 v = *(const float4*)(s + (size_t)rel * 4);
    ushort4 o;
    o.x = f2bf(v.x); o.y = f2bf(v.y); o.z = f2bf(v.z); o.w = f2bf(v.w);
    *(ushort4*)(d + (size_t)rel * 4) = o;
}

// shared swizzle helpers (rule-21 involution: linear gload_lds dest, inverse-swizzled
// global source, swizzled ds_read)
#define LADDR(row, ko) ((row) * 64 + ((ko) ^ (((row) & 7) << 3)))
#define GSB   __builtin_amdgcn_sched_barrier(0)
#define GBAR  __builtin_amdgcn_s_barrier()
#define LGKM0 do { asm volatile("s_waitcnt lgkmcnt(0)" ::: "memory"); GSB; } while (0)

__device__ __forceinline__ void stage1(u16* lds, const u16* g, int row0,
                                       int kt, int K, int tid) {
    const int rr = tid >> 3;
    const int chunk = (tid & 7) ^ (rr & 7);
    gload_lds16(g + (size_t)(row0 + rr) * K + kt + chunk * 8,
                lds + (row0 + (tid >> 6) * 8) * 64);
}

// ======================= 128x192 2-barrier bf16 GEMM (QKV projection) ================
// 512 blocks = 2 blocks/CU (80 KiB LDS); validated R12.
__global__ __launch_bounds__(512, 2)
void gemm_qkv(const u16* __restrict__ A, const u16* __restrict__ Bt,
              float* __restrict__ C, int M, int N, int K) {
    __shared__ u16 As2[2 * 8192];    // [buf][128][64]
    __shared__ u16 Bs2[2 * 12288];   // [buf][192][64]
    const int tid = threadIdx.x;
    const int w = tid >> 6, lane = tid & 63;
    const int lr = lane & 15, quad = lane >> 4;
    const int qo = quad * 8;
    const int wr = w >> 2, wc = w & 3;
    const int am = wr * 64;
    const int bn = wc * 48;

    const int nbx = N / 192;         // 16
    int wg = blockIdx.x;
    {
        const int nwg = gridDim.x;
        const int q = nwg >> 3, r = nwg & 7;
        const int xcd = wg & 7, loc = wg >> 3;
        wg = (xcd < r ? xcd * (q + 1) : r * (q + 1) + (xcd - r) * q) + loc;
    }
    const int n0 = (wg % nbx) * 192;
    const int m0 = (wg / nbx) * 128;

    const u16* gA = A + (size_t)m0 * K;
    const u16* gB = Bt + (size_t)n0 * K;
    const int nt = K >> 6;

    f32x4 acc[4][3];
#pragma unroll
    for (int mi = 0; mi < 4; mi++)
#pragma unroll
        for (int ni = 0; ni < 3; ni++)
            acc[mi][ni] = (f32x4){0.f, 0.f, 0.f, 0.f};

    short8 af[4][2], bf[3][2];

    stage1(As2, gA, 0, 0, K, tid);
    stage1(As2, gA, 64, 0, K, tid);
#pragma unroll
    for (int r = 0; r < 3; r++) stage1(Bs2, gB, r * 64, 0, K, tid);
    if (nt > 1) {
        stage1(As2 + 8192, gA, 0, 64, K, tid);
        stage1(As2 + 8192, gA, 64, 64, K, tid);
        stage1(Bs2 + 12288, gB, 0, 64, K, tid);
        stage1(Bs2 + 12288, gB, 64, 64, K, tid);
        asm volatile("s_waitcnt vmcnt(4)" ::: "memory");
    } else {
        asm volatile("s_waitcnt vmcnt(0)" ::: "memory");
    }
    GSB; GBAR;

    for (int t = 0; t < nt; ++t) {
        const int pb = t & 1;
        u16* Ap = As2 + pb * 8192;
        u16* Bp = Bs2 + pb * 12288;
        u16* Bn = Bs2 + (pb ^ 1) * 12288;
        const int kt1 = (t + 1) << 6, kt2 = (t + 2) << 6;

#pragma unroll
        for (int mi = 0; mi < 4; mi++)
#pragma unroll
            for (int kk = 0; kk < 2; kk++)
                af[mi][kk] = *(const short8*)&Ap[LADDR(am + mi * 16 + lr, kk * 32 + qo)];
#pragma unroll
        for (int ni = 0; ni < 3; ni++)
#pragma unroll
            for (int kk = 0; kk < 2; kk++)
                bf[ni][kk] = *(const short8*)&Bp[LADDR(bn + ni * 16 + lr, kk * 32 + qo)];
        if (t + 1 < nt) stage1(Bn, gB, 128, kt1, K, tid);
        GSB; GBAR; LGKM0;
        __builtin_amdgcn_s_setprio(1);
#pragma unroll
        for (int mi = 0; mi < 4; mi++)
#pragma unroll
            for (int ni = 0; ni < 3; ni++)
#pragma unroll
                for (int kk = 0; kk < 2; kk++)
                    acc[mi][ni] = __builtin_amdgcn_mfma_f32_16x16x32_bf16(
                        af[mi][kk], bf[ni][kk], acc[mi][ni], 0, 0, 0);
        __builtin_amdgcn_s_setprio(0);
        if (t + 2 < nt) {
            stage1(Ap, gA, 0, kt2, K, tid);
            stage1(Ap, gA, 64, kt2, K, tid);
            stage1(Bp, gB, 0, kt2, K, tid);
            stage1(Bp, gB, 64, kt2, K, tid);
        }
        if (t + 2 >= nt) {
            asm volatile("s_waitcnt vmcnt(0)" ::: "memory");
        } else {
            asm volatile("s_waitcnt vmcnt(4)" ::: "memory");
        }
        GSB; GBAR;
    }

#pragma unroll
    for (int mi = 0; mi < 4; mi++)
#pragma unroll
        for (int ni = 0; ni < 3; ni++) {
            const int row = m0 + am + mi * 16 + quad * 4;
            const int col = n0 + bn + ni * 16 + lr;
            f32x4 v = acc[mi][ni];
            C[(size_t)(row + 0) * N + col] = v[0];
            C[(size_t)(row + 1) * N + col] = v[1];
            C[(size_t)(row + 2) * N + col] = v[2];
            C[(size_t)(row + 3) * N + col] = v[3];
        }
}

// ======================= 128x128 2-barrier bf16 GEMM (output projection) =============
__global__ __launch_bounds__(512, 2)
void gemm_proj(const u16* __restrict__ A, const u16* __restrict__ Bt,
               float* __restrict__ C, int M, int N, int K) {
    __shared__ u16 As2[2 * 8192];
    __shared__ u16 Bs2[2 * 8192];
    const int tid = threadIdx.x;
    const int w = tid >> 6, lane = tid & 63;
    const int lr = lane & 15, quad = lane >> 4;
    const int qo = quad * 8;
    const int wr = w >> 2, wc = w & 3;
    const int am = wr * 64;
    const int bn = wc * 32;

    const int nbx = N >> 7;          // 16
    int wg = blockIdx.x;
    {
        const int nwg = gridDim.x;
        const int q = nwg >> 3, r = nwg & 7;
        const int xcd = wg & 7, loc = wg >> 3;
        wg = (xcd < r ? xcd * (q + 1) : r * (q + 1) + (xcd - r) * q) + loc;
    }
    const int n0 = (wg % nbx) << 7;
    const int m0 = (wg / nbx) << 7;

    const u16* gA = A + (size_t)m0 * K;
    const u16* gB = Bt + (size_t)n0 * K;
    const int nt = K >> 6;

    f32x4 acc[4][2];
#pragma unroll
    for (int mi = 0; mi < 4; mi++)
#pragma unroll
        for (int ni = 0; ni < 2; ni++)
            acc[mi][ni] = (f32x4){0.f, 0.f, 0.f, 0.f};

    short8 af[4][2], bf[2][2];

    stage1(As2, gA, 0, 0, K, tid);
    stage1(As2, gA, 64, 0, K, tid);
    stage1(Bs2, gB, 0, 0, K, tid);
    stage1(Bs2, gB, 64, 0, K, tid);
    if (nt > 1) {
        stage1(As2 + 8192, gA, 0, 64, K, tid);
        stage1(As2 + 8192, gA, 64, 64, K, tid);
        stage1(Bs2 + 8192, gB, 0, 64, K, tid);
        asm volatile("s_waitcnt vmcnt(3)" ::: "memory");
    } else {
        asm volatile("s_waitcnt vmcnt(0)" ::: "memory");
    }
    GSB; GBAR;

    for (int t = 0; t < nt; ++t) {
        const int pb = t & 1;
        u16* Ap = As2 + pb * 8192;
        u16* Bp = Bs2 + pb * 8192;
        u16* Bn = Bs2 + (pb ^ 1) * 8192;
        const int kt1 = (t + 1) << 6, kt2 = (t + 2) << 6;

#pragma unroll
        for (int mi = 0; mi < 4; mi++)
#pragma unroll
            for (int kk = 0; kk < 2; kk++)
                af[mi][kk] = *(const short8*)&Ap[LADDR(am + mi * 16 + lr, kk * 32 + qo)];
#pragma unroll
        for (int ni = 0; ni < 2; ni++)
#pragma unroll
            for (int kk = 0; kk < 2; kk++)
                bf[ni][kk] = *(const short8*)&Bp[LADDR(bn + ni * 16 + lr, kk * 32 + qo)];
        if (t + 1 < nt) stage1(Bn, gB, 64, kt1, K, tid);
        GSB; GBAR; LGKM0;
        __builtin_amdgcn_s_setprio(1);
#pragma unroll
        for (int mi = 0; mi < 4; mi++)
#pragma unroll
            for (int ni = 0; ni < 2; ni++)
#pragma unroll
                for (int kk = 0; kk < 2; kk++)
                    acc[mi][ni] = __builtin_amdgcn_mfma_f32_16x16x32_bf16(
                        af[mi][kk], bf[ni][kk], acc[mi][ni], 0, 0, 0);
        __builtin_amdgcn_s_setprio(0);
        if (t + 2 < nt) {
            stage1(Ap, gA, 0, kt2, K, tid);
            stage1(Ap, gA, 64, kt2, K, tid);
            stage1(Bp, gB, 0, kt2, K, tid);
        }
        if (t + 2 >= nt) {
            asm volatile("s_waitcnt vmcnt(0)" ::: "memory");
        } else {
            asm volatile("s_waitcnt vmcnt(3)" ::: "memory");
        }
        GSB; GBAR;
    }

#pragma unroll
    for (int mi = 0; mi < 4; mi++)
#pragma unroll
        for (int ni = 0; ni < 2; ni++) {
            const int row = m0 + am + mi * 16 + quad * 4;
            const int col = n0 + bn + ni * 16 + lr;
            f32x4 v = acc[mi][ni];
            C[(size_t)(row + 0) * N + col] = v[0];
            C[(size_t)(row + 1) * N + col] = v[1];
            C[(size_t)(row + 2) * N + col] = v[2];
            C[(size_t)(row + 3) * N + col] = v[3];
        }
}

// ------- prep: Q+K RMSNorm+RoPE (LUT — no sincosf) + V-transpose ----------------
// Q restored to prep (R13 structure) but using the cos/sin LUT (R14 technique):
// best measured attn (58.7us, zero conflicts) + cheap memory-bound prep.
#define LDT 65
#define RMSBLKS 20480
__global__ __launch_bounds__(256)
void prep(const float* __restrict__ qkv,
          const float* __restrict__ qw, const float* __restrict__ kw,
          const float* __restrict__ tab,
          u16* __restrict__ qdst, u16* __restrict__ kdst, u16* __restrict__ vdst) {
    __shared__ u16 Ts[128 * LDT];
    if (blockIdx.x < RMSBLKS) {
        int p = blockIdx.x * 4 + (threadIdx.x >> 6);
        int lane = threadIdx.x & 63;
        const float* src; const float* w; u16* dst; int HH;
        if (p < NTOK * NH) { src = qkv; w = qw; dst = qdst; HH = NH; }
        else { p -= NTOK * NH; src = qkv + 2048; w = kw; dst = kdst; HH = NKVH; }
        int n = p / HH;
        int h = p - n * HH;
        int b = n >> 11;
        int s = n & 2047;
        const float* row = src + (size_t)n * NQKV + h * HD;
        float t1 = row[lane];
        float t2 = row[lane + 64];
        float ss = t1 * t1 + t2 * t2;
#pragma unroll
        for (int o = 1; o < 64; o <<= 1) ss += __shfl_xor(ss, o);
        float r = rsqrtf(ss * (1.f / 128.f) + 1e-6f);
        float a1 = t1 * r * w[lane];
        float a2 = t2 * r * w[lane + 64];
        float2 csn = ((const float2*)tab)[(s << 6) + lane];
        float o1 = a1 * csn.x - a2 * csn.y;
        float o2 = a2 * csn.x + a1 * csn.y;
        size_t base = (((size_t)(b * HH + h)) * S + s) * HD;
        dst[base + lane] = f2bf(o1);
        dst[base + 64 + lane] = f2bf(o2);
    } else {
        const int idx = blockIdx.x - RMSBLKS;
        const int t = threadIdx.x;
        const int s0 = (idx & 31) * 64;
        const int kh = (idx >> 5) & 3;
        const int b = idx >> 7;
        const float* base = qkv + ((size_t)(b * S + s0)) * NQKV + 2560 + kh * HD;
#pragma unroll
        for (int i = 0; i < 8; i++) {
            int ii = i * 256 + t;
            int r = ii >> 5, c4 = (ii & 31) * 4;
            float4 v = *(const float4*)(base + (size_t)r * NQKV + c4);
            Ts[(c4 + 0) * LDT + r] = f2bf(v.x);
            Ts[(c4 + 1) * LDT + r] = f2bf(v.y);
            Ts[(c4 + 2) * LDT + r] = f2bf(v.z);
            Ts[(c4 + 3) * LDT + r] = f2bf(v.w);
        }
        __syncthreads();
        u16* obase = vdst + ((size_t)(b * NKVH + kh) * HD) * S + s0;
#pragma unroll
        for (int i = 0; i < 4; i++) {
            int ii = i * 256 + t;
            int d = ii >> 3, s8 = (ii & 7) * 8;
            const u16* row = &Ts[d * LDT + s8];
            short8 o;
#pragma unroll
            for (int j = 0; j < 8; j++) o[j] = (short)row[j];
            *(short8*)(obase + (size_t)d * S + s8) = o;
        }
    }
}

// ---------------- MFMA flash attention, CU-balanced 1024-block grid ----------------
// R8/R13 best-measured version (58.7us): bf16 qaa input, zero LDS conflicts.
// Balanced decode: same-CU bids {p,p+256,p+512,p+768} -> tile counts
// {17,17,9+j,8-j} = 51/CU; same-CU blocks share (b,h) K/V stream (L2 reuse).
// Fused-Q prologue (R14/R15) REVERTED: +7.7us on attn critical path (fp32 Q reads
// + LUT gather + LDS conflicts) > its prep savings once prep uses the LUT.
#define KSX(key, cb) ((key) * 128 + ((((cb) ^ ((key) & 15))) * 8))
#define VSX(d, cb)   ((d) * 64 + ((((cb) ^ ((d) & 7))) * 8))
#define PSX(row, cb) ((row) * 64 + ((((cb) ^ ((row) & 7))) * 8))
#define QBLK 64

__global__ __launch_bounds__(256, 4)
void attn_mfma(const u16* __restrict__ qa, const u16* __restrict__ ka,
               const u16* __restrict__ vt, u16* __restrict__ out) {
    __shared__ u16 Ks[64 * 128];
    __shared__ u16 Vs[128 * 64];
    __shared__ u16 Ps[64 * 64];
    const int tid = threadIdx.x;
    const int w = tid >> 6, lane = tid & 63;
    const int lr = lane & 15, quad = lane >> 4;

    const int bid = blockIdx.x;
    const int g = bid >> 8, p = bid & 255;
    const int j = p >> 5, hb = p & 31;
    int qt;
    if (g == 0) qt = 31 - j;
    else if (g == 1) qt = 23 - j;
    else if (g == 2) qt = 8 + j;
    else qt = 7 - j;
    const int h = hb >> 1, b = hb & 1;
    const int kh = h >> 2;
    const int q0 = qt * QBLK;
    const int qg0 = q0 + w * 16;          // this wave's 16 queries

    const float KQK = 0.0051006974f;      // 2/(sqrt(128)*50) * log2(e)
    const float KP  = -144.26950408889634f; // -100 * log2(e)

    const u16* kbase0 = ka + (((size_t)(b * NKVH + kh)) * S) * HD;
    const u16* vtbase0 = vt + ((size_t)(b * NKVH + kh) * HD) * S;

    short8 qf[4];
    {
        const u16* qrow = qa + (((size_t)(b * NH + h)) * S + qg0 + lr) * HD;
#pragma unroll
        for (int c = 0; c < 4; c++)
            qf[c] = *(const short8*)(qrow + c * 32 + quad * 8);
    }

    f32x4 O[8];
#pragma unroll
    for (int dt = 0; dt < 8; dt++) O[dt] = (f32x4){0.f, 0.f, 0.f, 0.f};
    float l[4] = {0.f, 0.f, 0.f, 0.f};

    const int jt0 = (q0 >= 1024) ? (q0 - 1024) : 0;
    const int jtend = q0;                 // diagonal tile
    const int qmin = qg0, qmax = qg0 + 15;

    for (int jt = jt0; jt <= jtend; jt += 64) {
        const u16* kbase = kbase0 + (size_t)jt * HD;
        const u16* vtbase = vtbase0 + jt;
        __syncthreads();
#pragma unroll
        for (int i = 0; i < 4; i++) {
            int idx = i * 256 + tid;
            int key = idx >> 4, cbk = (idx & 15) ^ (key & 15);
            gload_lds16(kbase + (size_t)key * HD + cbk * 8,
                        &Ks[(i * 256 + w * 64) * 8]);
            int dd = idx >> 3, cbv = (idx & 7) ^ (dd & 7);
            gload_lds16(vtbase + (size_t)dd * S + cbv * 8,
                        &Vs[(i * 256 + w * 64) * 8]);
        }
        __syncthreads();

        u16* Pw = &Ps[w * 16 * 64];
        bool any = false;

#pragma unroll
        for (int kt = 0; kt < 4; kt++) {
            const int keymin = jt + kt * 16;
            bool need = (keymin <= qmax) && (keymin + 15 >= qmin - 1023);
            bool full = (keymin + 15 <= qmin) && (keymin >= qmax - 1023);
            if (need) {
                any = true;
                f32x4 a = (f32x4){0.f, 0.f, 0.f, 0.f};
                __builtin_amdgcn_s_setprio(1);
#pragma unroll
                for (int c = 0; c < 4; c++) {
                    short8 kf = *(const short8*)(&Ks[KSX(kt * 16 + lr, 4 * c + quad)]);
                    a = __builtin_amdgcn_mfma_f32_16x16x32_bf16(qf[c], kf, a, 0, 0, 0);
                }
                __builtin_amdgcn_s_setprio(0);
#pragma unroll
                for (int r = 0; r < 4; r++) {
                    float t = __builtin_amdgcn_exp2f(a[r] * KQK);
                    float p2 = __builtin_amdgcn_exp2f(
                        KP * __builtin_amdgcn_rcpf(t + 1.f));
                    if (!full) {
                        int rel = keymin + lr - (qg0 + quad * 4 + r);
                        bool valid = (rel <= 0) && (rel > -1024);
                        p2 = valid ? p2 : 0.f;
                    }
                    l[r] += p2;
                    Pw[PSX(quad * 4 + r, kt * 2 + (lr >> 3)) + (lr & 7)] =
                        (u16)(__float_as_uint(p2) >> 16);
                }
            } else {
#pragma unroll
                for (int r = 0; r < 4; r++)
                    Pw[PSX(quad * 4 + r, kt * 2 + (lr >> 3)) + (lr & 7)] = 0;
            }
        }

        if (any) {
            __builtin_amdgcn_s_setprio(1);
#pragma unroll
            for (int c2 = 0; c2 < 2; c2++) {
                short8 pf = *(const short8*)(&Pw[PSX(lr, c2 * 4 + quad)]);
#pragma unroll
                for (int dt = 0; dt < 8; dt++) {
                    short8 vf = *(const short8*)(&Vs[VSX(dt * 16 + lr, c2 * 4 + quad)]);
                    O[dt] = __builtin_amdgcn_mfma_f32_16x16x32_bf16(pf, vf, O[dt], 0, 0, 0);
                }
            }
            __builtin_amdgcn_s_setprio(0);
        }
    }

#pragma unroll
    for (int r = 0; r < 4; r++) {
        l[r] += __shfl_xor(l[r], 1);
        l[r] += __shfl_xor(l[r], 2);
        l[r] += __shfl_xor(l[r], 4);
        l[r] += __shfl_xor(l[r], 8);
    }
#pragma unroll
    for (int r = 0; r < 4; r++) {
        float inv = 1.f / l[r];
        u16* orow = out + ((size_t)(b * S + qg0 + quad * 4 + r)) * E + h * HD;
#pragma unroll
        for (int dt = 0; dt < 8; dt++)
            orow[dt * 16 + lr] = f2bf(O[dt][r] * inv);
    }
}

// ---------------- residual + LayerNorm ----------------
__global__ __launch_bounds__(256)
void ln_kernel(const float* __restrict__ x, const float* __restrict__ pr,
               const float* __restrict__ g, const float* __restrict__ be,
               float* __restrict__ out) {
    int n = blockIdx.x;
    int tid = threadIdx.x;
    const float* xr = x + (size_t)n * E;
    const float* p = pr + (size_t)n * E;
    float y[8];
    float s = 0.f, ss = 0.f;
#pragma unroll
    for (int i = 0; i < 2; i++) {
        float4 a = *(const float4*)(xr + tid * 8 + i * 4);
        float4 b = *(const float4*)(p + tid * 8 + i * 4);
        float v0 = a.x + b.x, v1 = a.y + b.y, v2 = a.z + b.z, v3 = a.w + b.w;
        y[i * 4 + 0] = v0; y[i * 4 + 1] = v1; y[i * 4 + 2] = v2; y[i * 4 + 3] = v3;
        s += v0 + v1 + v2 + v3;
        ss += v0 * v0 + v1 * v1 + v2 * v2 + v3 * v3;
    }
#pragma unroll
    for (int o = 1; o < 64; o <<= 1) {
        s += __shfl_xor(s, o);
        ss += __shfl_xor(ss, o);
    }
    __shared__ float r0[4], r1[4];
    int w = tid >> 6;
    if ((tid & 63) == 0) { r0[w] = s; r1[w] = ss; }
    __syncthreads();
    s = r0[0] + r0[1] + r0[2] + r0[3];
    ss = r1[0] + r1[1] + r1[2] + r1[3];
    float mu = s * (1.f / 2048.f);
    float var = ss * (1.f / 2048.f) - mu * mu;
    float rs = rsqrtf(var + 1e-5f);
    float* orow = out + (size_t)n * E;
#pragma unroll
    for (int i = 0; i < 8; i++) {
        int c = tid * 8 + i;
        orow[c] = (y[i] - mu) * rs * g[c] + be[c];
    }
}

// ---------------- launch ----------------
extern "C" void kernel_launch(void* const* d_in, const int* in_sizes, int n_in,
                              void* d_out, int out_size, void* d_ws, size_t ws_size,
                              hipStream_t stream) {
    (void)in_sizes; (void)n_in; (void)out_size; (void)ws_size;
    const float* x   = (const float*)d_in[0];
    const float* Wq  = (const float*)d_in[1];
    const float* Wk  = (const float*)d_in[2];
    const float* Wv  = (const float*)d_in[3];
    const float* Wo  = (const float*)d_in[4];
    const float* qnw = (const float*)d_in[5];
    const float* knw = (const float*)d_in[6];
    const float* lng = (const float*)d_in[7];
    const float* lnb = (const float*)d_in[8];
    float* out = (float*)d_out;

    char* ws = (char*)d_ws;
    size_t off = 0;
    auto alloc = [&](size_t bytes) -> char* {
        char* pp = ws + off;
        off = (off + bytes + 255) & ~(size_t)255;
        return pp;
    };
    u16*  xb     = (u16*)alloc((size_t)NTOK * E * 2);       // later reused as attn_out
    u16*  Wqkvb  = (u16*)alloc((size_t)NQKV * E * 2);       // [Wq; Wk; Wv]
    u16*  Wob    = (u16*)alloc((size_t)E * E * 2);
    float* qkvraw= (float*)alloc((size_t)NTOK * NQKV * 4);  // 50.3MB; reused as proj
    u16*  qaa    = (u16*)alloc((size_t)NTOK * E * 2);
    u16*  kaa    = (u16*)alloc((size_t)NTOK * 512 * 2);
    u16*  vtt    = (u16*)alloc((size_t)NTOK * 512 * 2);
    float* tab   = (float*)alloc((size_t)S * 64 * 8);       // RoPE cos/sin LUT, 1MB
    u16*  attn_o = xb;
    float* proj  = qkvraw;   // qkvraw dead after prep/attn consume it

    cast5<<<dim3(CASTBLKS + 512), 256, 0, stream>>>(x, Wq, Wk, Wv, Wo, xb, Wqkvb,
                                                    Wob, tab);

    // 128x192 tiles -> 32x16 = 512 blocks (2 blocks/CU), 2-barrier K-loop
    gemm_qkv<<<dim3(512), 512, 0, stream>>>(xb, Wqkvb, qkvraw, NTOK, NQKV, E);

    // Q+K rmsrope via LUT + V transpose
    prep<<<dim3(RMSBLKS + 256), 256, 0, stream>>>(qkvraw, qnw, knw, tab,
                                                  qaa, kaa, vtt);

    // CU-balanced 1024-block grid (4/CU; per-CU work = 51 tiles for every CU)
    attn_mfma<<<dim3(1024), 256, 0, stream>>>(qaa, kaa, vtt, attn_o);

    // 128x128 tiles -> 32x16 = 512 blocks (2 blocks/CU), 2-barrier K-loop
    gemm_proj<<<dim3(512), 512, 0, stream>>>(attn_o, Wob, proj, NTOK, E, E);

    ln_kernel<<<dim3(NTOK), 256, 0, stream>>>(x, proj, lng, lnb, out);
}